// Round 1
// baseline (200.941 us; speedup 1.0000x reference)
//
#include <hip/hip_runtime.h>
#include <math.h>

#define BB 16
#define SS 8192
#define HH 256
#define MM 16
#define P1 64
#define LS1 (SS / P1)   // 128
#define P3 64
#define LS3 (SS / P3)   // 128

// ws layout (floats): T twiddle table [SS][2*MM] at 0 (262144 floats = 1 MB),
// AB coefficients [BB][MM][2][HH] at SS*2*MM (131072 floats = 0.5 MB).
// Partial DFT sums Xp [BB][P1][MM][2][HH] (8.4M floats) live in d_out scratch,
// consumed by k_mix before k_synth overwrites d_out.

// T[s*32 + 2k] = cos(2*pi*k*s/SS), T[s*32+2k+1] = sin(2*pi*k*s/SS)
__global__ __launch_bounds__(256) void k_twiddle(float* __restrict__ T) {
    int idx = blockIdx.x * 256 + threadIdx.x;   // 0 .. SS*MM-1
    if (idx >= SS * MM) return;
    int s = idx >> 4, k = idx & 15;
    int r = (k * s) & (SS - 1);                 // exact angle reduction
    float th = (float)r * (6.28318530717958647692f / (float)SS);
    float sn, cn;
    sincosf(th, &sn, &cn);
    T[s * 32 + 2 * k]     = cn;
    T[s * 32 + 2 * k + 1] = sn;
}

// Stage 1: pruned forward DFT, partial over s-chunk p.
// Xp[((b*P1+p)*MM + k)*2*HH + c*HH + h],  c=0: sum x*cos, c=1: sum x*sin
__global__ __launch_bounds__(256) void k_dft(const float* __restrict__ x,
                                             const float* __restrict__ T,
                                             float* __restrict__ Xp) {
    const int p = blockIdx.x, b = blockIdx.y, h = threadIdx.x;
    float cs[MM], sn[MM];
#pragma unroll
    for (int k = 0; k < MM; k++) { cs[k] = 0.f; sn[k] = 0.f; }

    const int s0 = p * LS1;
    const float* xp = x + ((size_t)b * SS + s0) * HH + h;

#pragma unroll 4
    for (int i = 0; i < LS1; i++) {
        float xv = xp[(size_t)i * HH];
        const float4* tw4 = (const float4*)(T + (size_t)(s0 + i) * 32);
#pragma unroll
        for (int j = 0; j < 8; j++) {
            float4 t = tw4[j];
            cs[2 * j]     = fmaf(xv, t.x, cs[2 * j]);
            sn[2 * j]     = fmaf(xv, t.y, sn[2 * j]);
            cs[2 * j + 1] = fmaf(xv, t.z, cs[2 * j + 1]);
            sn[2 * j + 1] = fmaf(xv, t.w, sn[2 * j + 1]);
        }
    }

    size_t base = ((size_t)(b * P1 + p) * MM) * (2 * HH) + h;
#pragma unroll
    for (int k = 0; k < MM; k++) {
        Xp[base + (size_t)k * (2 * HH)]      = cs[k];
        Xp[base + (size_t)k * (2 * HH) + HH] = sn[k];
    }
}

// Stage 2: reduce partials over p, then complex mix with W, emit A/B coefs.
// X = cs - i*sn.  O[k'] = sum_h X[h] * (wr + i*wi)[h,k',m]
// A = scale*Re(O), Bc = -scale*Im(O), scale = (m==0?1:2)/SS
__global__ __launch_bounds__(256) void k_mix(const float* __restrict__ Xp,
                                             const float* __restrict__ wr,
                                             const float* __restrict__ wi,
                                             float* __restrict__ AB) {
    const int m = blockIdx.x, b = blockIdx.y, t = threadIdx.x;
    __shared__ float sX[2][HH];

    // phase A: reduce over p for h = t
    float sc = 0.f, ssum = 0.f;
    size_t base = (((size_t)b * P1) * MM + m) * (2 * HH) + t;
    for (int p = 0; p < P1; p++) {
        sc   += Xp[base + (size_t)p * MM * 2 * HH];
        ssum += Xp[base + (size_t)p * MM * 2 * HH + HH];
    }
    sX[0][t] = sc;
    sX[1][t] = ssum;
    __syncthreads();

    // phase B: t = output neuron k'
    float re = 0.f, im = 0.f;
    for (int h = 0; h < HH; h++) {
        float xr = sX[0][h];
        float xs = sX[1][h];            // true Xim = -xs
        size_t widx = (size_t)h * (HH * MM) + (size_t)t * MM + m;
        float a = wr[widx], bw = wi[widx];
        re = fmaf(xr, a, re);  re = fmaf(xs, bw, re);   // xr*a + xs*bw
        im = fmaf(xr, bw, im); im = fmaf(-xs, a, im);   // xr*bw - xs*a
    }
    float scale = (m == 0 ? 1.f : 2.f) / (float)SS;
    size_t o = (((size_t)b * MM + m) * 2) * HH + t;
    AB[o]      = scale * re;
    AB[o + HH] = -scale * im;
}

// Stage 3: sparse inverse synthesis + exact GELU.
// y[b,s,h] = sum_k A[k]*cos(2pi k s/S) + Bc[k]*sin(2pi k s/S); out = gelu(y)
__global__ __launch_bounds__(256) void k_synth(const float* __restrict__ AB,
                                               const float* __restrict__ T,
                                               float* __restrict__ out) {
    const int p = blockIdx.x, b = blockIdx.y, h = threadIdx.x;
    float a[MM], bc[MM];
#pragma unroll
    for (int k = 0; k < MM; k++) {
        size_t o = (((size_t)b * MM + k) * 2) * HH + h;
        a[k]  = AB[o];
        bc[k] = AB[o + HH];
    }
    const int s0 = p * LS3;
    float* yp = out + ((size_t)b * SS + s0) * HH + h;

#pragma unroll 2
    for (int i = 0; i < LS3; i++) {
        const float4* tw4 = (const float4*)(T + (size_t)(s0 + i) * 32);
        float acc0 = 0.f, acc1 = 0.f, acc2 = 0.f, acc3 = 0.f;
#pragma unroll
        for (int j = 0; j < 8; j++) {
            float4 t = tw4[j];
            float p0 = fmaf(a[2 * j], t.x, bc[2 * j] * t.y);
            float p1 = fmaf(a[2 * j + 1], t.z, bc[2 * j + 1] * t.w);
            if (j < 2)      { acc0 += p0; acc0 += p1; }
            else if (j < 4) { acc1 += p0; acc1 += p1; }
            else if (j < 6) { acc2 += p0; acc2 += p1; }
            else            { acc3 += p0; acc3 += p1; }
        }
        float y = (acc0 + acc1) + (acc2 + acc3);
        float g = 0.5f * y * (1.f + erff(y * 0.70710678118654752f));
        yp[(size_t)i * HH] = g;
    }
}

extern "C" void kernel_launch(void* const* d_in, const int* in_sizes, int n_in,
                              void* d_out, int out_size, void* d_ws, size_t ws_size,
                              hipStream_t stream) {
    const float* x   = (const float*)d_in[0];
    const float* w_r = (const float*)d_in[1];
    const float* w_i = (const float*)d_in[2];
    float* out = (float*)d_out;
    float* ws  = (float*)d_ws;

    float* T  = ws;                           // SS*32 floats
    float* AB = ws + (size_t)SS * 32;         // BB*MM*2*HH floats
    float* Xp = out;                          // scratch in d_out (overwritten by k_synth)

    hipLaunchKernelGGL(k_twiddle, dim3((SS * MM + 255) / 256), dim3(256), 0, stream, T);
    hipLaunchKernelGGL(k_dft,   dim3(P1, BB), dim3(256), 0, stream, x, T, Xp);
    hipLaunchKernelGGL(k_mix,   dim3(MM, BB), dim3(256), 0, stream, Xp, w_r, w_i, AB);
    hipLaunchKernelGGL(k_synth, dim3(P3, BB), dim3(256), 0, stream, AB, T, out);
}

// Round 2
// 155.551 us; speedup vs baseline: 1.2918x; 1.2918x over previous
//
#include <hip/hip_runtime.h>
#include <math.h>

#define BB 16
#define SS 8192
#define HH 256
#define MM 16
#define P1 64
#define LS1 (SS / P1)   // 128
#define P3 64
#define LS3 (SS / P3)   // 128

// ws layout (floats): T [SS][32] at 0 (262144), AB [BB][MM][2][HH] at 262144
// (131072), Xs [BB][MM][2][HH] at 393216 (131072).  Total 2 MB.
// d_out scratch: Xp [BB][P1][MM][2][HH] at 0 (8.4M floats, 33.5 MB),
// Wt_r at float-offset 16M, Wt_i at 17M (1M floats each).  All consumed
// before k_synth overwrites d_out.

// T[s*32 + 2k] = cos(2*pi*k*s/SS), T[s*32+2k+1] = sin(2*pi*k*s/SS)
__global__ __launch_bounds__(256) void k_twiddle(float* __restrict__ T) {
    int idx = blockIdx.x * 256 + threadIdx.x;   // 0 .. SS*MM-1
    if (idx >= SS * MM) return;
    int s = idx >> 4, k = idx & 15;
    int r = (k * s) & (SS - 1);                 // exact angle reduction
    float th = (float)r * (6.28318530717958647692f / (float)SS);
    float sn, cn;
    sincosf(th, &sn, &cn);
    T[s * 32 + 2 * k]     = cn;
    T[s * 32 + 2 * k + 1] = sn;
}

// Transpose W: Wt[m][h][k'] = w[h][k'][m].  One block per (h, which-array).
__global__ __launch_bounds__(256) void k_wt(const float* __restrict__ wr,
                                            const float* __restrict__ wi,
                                            float* __restrict__ Wtr,
                                            float* __restrict__ Wti) {
    __shared__ float lds[4096 + 256];           // +pad every 16
    const int h = blockIdx.x, t = threadIdx.x;
    const float* src = (blockIdx.y == 0 ? wr : wi) + (size_t)h * 4096;
    float* dst = (blockIdx.y == 0 ? Wtr : Wti);
#pragma unroll
    for (int j = 0; j < 16; j++) {
        int i = j * 256 + t;
        lds[i + (i >> 4)] = src[i];             // coalesced read, ~2-way LDS
    }
    __syncthreads();
#pragma unroll
    for (int m = 0; m < 16; m++) {
        int i = t * 16 + m;                     // padded idx = t*17+m: conflict-free
        dst[(size_t)m * (HH * HH) + (size_t)h * HH + t] = lds[i + (i >> 4)];
    }
}

// Stage 1: pruned forward DFT, partial over s-chunk p.
__global__ __launch_bounds__(256) void k_dft(const float* __restrict__ x,
                                             const float* __restrict__ T,
                                             float* __restrict__ Xp) {
    const int p = blockIdx.x, b = blockIdx.y, h = threadIdx.x;
    float cs[MM], sn[MM];
#pragma unroll
    for (int k = 0; k < MM; k++) { cs[k] = 0.f; sn[k] = 0.f; }

    const int s0 = p * LS1;
    const float* xp = x + ((size_t)b * SS + s0) * HH + h;

#pragma unroll 4
    for (int i = 0; i < LS1; i++) {
        float xv = xp[(size_t)i * HH];
        const float4* tw4 = (const float4*)(T + (size_t)(s0 + i) * 32);
#pragma unroll
        for (int j = 0; j < 8; j++) {
            float4 t = tw4[j];                  // wave-uniform -> scalar loads
            cs[2 * j]     = fmaf(xv, t.x, cs[2 * j]);
            sn[2 * j]     = fmaf(xv, t.y, sn[2 * j]);
            cs[2 * j + 1] = fmaf(xv, t.z, cs[2 * j + 1]);
            sn[2 * j + 1] = fmaf(xv, t.w, sn[2 * j + 1]);
        }
    }

    size_t base = ((size_t)(b * P1 + p) * MM) * (2 * HH) + h;
#pragma unroll
    for (int k = 0; k < MM; k++) {
        Xp[base + (size_t)k * (2 * HH)]      = cs[k];
        Xp[base + (size_t)k * (2 * HH) + HH] = sn[k];
    }
}

// Stage 2a: reduce partials over p.  Xs[b][m][c][h] = sum_p Xp[b][p][m][c][h]
__global__ __launch_bounds__(256) void k_reduce(const float* __restrict__ Xp,
                                                float* __restrict__ Xs) {
    const int t = blockIdx.x * 256 + threadIdx.x;   // 0..32767 (x4 floats)
    const int INNER = MM * 2 * HH;                  // 8192
    int idx4 = t * 4;
    int inner = idx4 & (INNER - 1);
    int b = idx4 / INNER;
    const float* src = Xp + ((size_t)b * P1) * INNER + inner;
    float4 s = make_float4(0.f, 0.f, 0.f, 0.f);
#pragma unroll 8
    for (int p = 0; p < P1; p++) {
        float4 v = *(const float4*)(src + (size_t)p * INNER);
        s.x += v.x; s.y += v.y; s.z += v.z; s.w += v.w;
    }
    *(float4*)(Xs + idx4) = s;
}

// Stage 2b: complex mix.  X = cs - i*sn;  O[k'] = sum_h X[h]*(wr+i*wi)[h,k',m]
// A = scale*Re(O), Bc = -scale*Im(O), scale = (m==0?1:2)/SS
__global__ __launch_bounds__(256) void k_mix2(const float* __restrict__ Xs,
                                              const float* __restrict__ Wtr,
                                              const float* __restrict__ Wti,
                                              float* __restrict__ AB) {
    const int m = blockIdx.x, b = blockIdx.y, t = threadIdx.x;
    __shared__ float xr_s[HH], xs_s[HH];
    size_t xbase = (((size_t)b * MM + m) * 2) * HH;
    xr_s[t] = Xs[xbase + t];
    xs_s[t] = Xs[xbase + HH + t];
    __syncthreads();

    const float* wr_m = Wtr + (size_t)m * (HH * HH);
    const float* wi_m = Wti + (size_t)m * (HH * HH);
    float re = 0.f, im = 0.f;
#pragma unroll 8
    for (int h = 0; h < HH; h++) {
        float a  = wr_m[(size_t)h * HH + t];    // lane-contiguous, 1KB/wave
        float bw = wi_m[(size_t)h * HH + t];
        float xr = xr_s[h];                     // LDS broadcast
        float xs = xs_s[h];
        re = fmaf(xr, a, re);  re = fmaf(xs, bw, re);
        im = fmaf(xr, bw, im); im = fmaf(-xs, a, im);
    }
    float scale = (m == 0 ? 1.f : 2.f) / (float)SS;
    size_t o = (((size_t)b * MM + m) * 2) * HH + t;
    AB[o]      = scale * re;
    AB[o + HH] = -scale * im;
}

// Stage 3: sparse inverse synthesis + exact GELU.
__global__ __launch_bounds__(256) void k_synth(const float* __restrict__ AB,
                                               const float* __restrict__ T,
                                               float* __restrict__ out) {
    const int p = blockIdx.x, b = blockIdx.y, h = threadIdx.x;
    float a[MM], bc[MM];
#pragma unroll
    for (int k = 0; k < MM; k++) {
        size_t o = (((size_t)b * MM + k) * 2) * HH + h;
        a[k]  = AB[o];
        bc[k] = AB[o + HH];
    }
    const int s0 = p * LS3;
    float* yp = out + ((size_t)b * SS + s0) * HH + h;

#pragma unroll 2
    for (int i = 0; i < LS3; i++) {
        const float4* tw4 = (const float4*)(T + (size_t)(s0 + i) * 32);
        float acc0 = 0.f, acc1 = 0.f, acc2 = 0.f, acc3 = 0.f;
#pragma unroll
        for (int j = 0; j < 8; j++) {
            float4 t = tw4[j];
            float p0 = fmaf(a[2 * j], t.x, bc[2 * j] * t.y);
            float p1 = fmaf(a[2 * j + 1], t.z, bc[2 * j + 1] * t.w);
            if (j < 2)      { acc0 += p0; acc0 += p1; }
            else if (j < 4) { acc1 += p0; acc1 += p1; }
            else if (j < 6) { acc2 += p0; acc2 += p1; }
            else            { acc3 += p0; acc3 += p1; }
        }
        float y = (acc0 + acc1) + (acc2 + acc3);
        float g = 0.5f * y * (1.f + erff(y * 0.70710678118654752f));
        yp[(size_t)i * HH] = g;
    }
}

extern "C" void kernel_launch(void* const* d_in, const int* in_sizes, int n_in,
                              void* d_out, int out_size, void* d_ws, size_t ws_size,
                              hipStream_t stream) {
    const float* x   = (const float*)d_in[0];
    const float* w_r = (const float*)d_in[1];
    const float* w_i = (const float*)d_in[2];
    float* out = (float*)d_out;
    float* ws  = (float*)d_ws;

    float* T   = ws;                            // 262144 floats
    float* AB  = ws + 262144;                   // 131072 floats
    float* Xs  = ws + 393216;                   // 131072 floats
    float* Xp  = out;                           // d_out scratch, 8.4M floats
    float* Wtr = out + (size_t)16 * 1024 * 1024; // d_out scratch, 1M floats
    float* Wti = out + (size_t)17 * 1024 * 1024; // d_out scratch, 1M floats

    hipLaunchKernelGGL(k_twiddle, dim3((SS * MM + 255) / 256), dim3(256), 0, stream, T);
    hipLaunchKernelGGL(k_wt,     dim3(HH, 2), dim3(256), 0, stream, w_r, w_i, Wtr, Wti);
    hipLaunchKernelGGL(k_dft,    dim3(P1, BB), dim3(256), 0, stream, x, T, Xp);
    hipLaunchKernelGGL(k_reduce, dim3(BB * MM * 2 * HH / 1024), dim3(256), 0, stream, Xp, Xs);
    hipLaunchKernelGGL(k_mix2,   dim3(MM, BB), dim3(256), 0, stream, Xs, Wtr, Wti, AB);
    hipLaunchKernelGGL(k_synth,  dim3(P3, BB), dim3(256), 0, stream, AB, T, out);
}

// Round 3
// 117.242 us; speedup vs baseline: 1.7139x; 1.3267x over previous
//
#include <hip/hip_runtime.h>
#include <math.h>

#define BB 16
#define SS 8192
#define HH 256
#define MM 16
#define NV 2049          // folded v range: 0..2048
#define DCH 32           // v per k_dft block
#define DNC 65           // k_dft chunks: 64 full + 1 edge (v=2048)
#define SCH 16           // v per k_synth block
#define SNC 129          // k_synth chunks: 128 full + 1 edge

// ws layout (floats): T [NV][32] at 0 (region reserved 262144), AB at 262144,
// Xs at 393216.  d_out scratch: Xp [BB][DNC][MM][2][HH] (8.5M floats) at 0,
// Wt_r at 16M floats, Wt_i at 17M floats — all consumed before k_synth writes.

// T[v*32 + 2k] = cos(2*pi*k*v/SS), T[v*32+2k+1] = sin(2*pi*k*v/SS), v<=2048
__global__ __launch_bounds__(256) void k_twiddle(float* __restrict__ T) {
    int idx = blockIdx.x * 256 + threadIdx.x;   // 0 .. NV*MM-1
    if (idx >= NV * MM) return;
    int v = idx >> 4, k = idx & 15;
    int r = (k * v) & (SS - 1);                 // exact angle reduction
    float th = (float)r * (6.28318530717958647692f / (float)SS);
    float sn, cn;
    sincosf(th, &sn, &cn);
    T[v * 32 + 2 * k]     = cn;
    T[v * 32 + 2 * k + 1] = sn;
}

// Transpose W: Wt[m][h][k'] = w[h][k'][m].
__global__ __launch_bounds__(256) void k_wt(const float* __restrict__ wr,
                                            const float* __restrict__ wi,
                                            float* __restrict__ Wtr,
                                            float* __restrict__ Wti) {
    __shared__ float lds[4096 + 256];
    const int h = blockIdx.x, t = threadIdx.x;
    const float* src = (blockIdx.y == 0 ? wr : wi) + (size_t)h * 4096;
    float* dst = (blockIdx.y == 0 ? Wtr : Wti);
#pragma unroll
    for (int j = 0; j < 16; j++) {
        int i = j * 256 + t;
        lds[i + (i >> 4)] = src[i];
    }
    __syncthreads();
#pragma unroll
    for (int m = 0; m < 16; m++) {
        int i = t * 16 + m;
        dst[(size_t)m * (HH * HH) + (size_t)h * HH + t] = lds[i + (i >> 4)];
    }
}

// Branchless exact-GELU via A&S 7.1.26 erf (|err| ~ 1.5e-7).
__device__ __forceinline__ float fast_gelu(float y) {
    float x  = fabsf(y) * 0.70710678118654752f;      // |y|/sqrt(2)
    float t  = __builtin_amdgcn_rcpf(fmaf(0.3275911f, x, 1.0f));
    float e  = __expf(-x * x);                        // ->0 for large x
    float p  = fmaf(fmaf(fmaf(fmaf(1.061405429f, t, -1.453152027f), t,
                   1.421413741f), t, -0.284496736f), t, 0.254829592f) * t;
    float erfabs = fmaf(-p, e, 1.0f);                 // erf(|y|/sqrt2)
    return fmaf(0.5f * fabsf(y), erfabs, 0.5f * y);   // 0.5y(1+sign(y)*erfabs)
}

// Stage 1: folded pruned DFT.  Rows {v, 8192-v, 4096-v, 4096+v} combined:
// even k: cs += c*(u+w), sn += s*(d+e); odd k: cs += c*(u-w), sn += s*(d-e)
// u=x_v+x_{S-v}, d=x_v-x_{S-v}, w=x_{S/2-v}+x_{S/2+v}, e=x_{S/2+v}-x_{S/2-v}
// v in {0,2048}: duplicate-index rows -> weight 0.5 (odd-c/even-s terms vanish).
__global__ __launch_bounds__(256) void k_dft(const float* __restrict__ x,
                                             const float* __restrict__ T,
                                             float* __restrict__ Xp) {
    const int c = blockIdx.x, b = blockIdx.y, h = threadIdx.x;
    float cs[MM], sn[MM];
#pragma unroll
    for (int k = 0; k < MM; k++) { cs[k] = 0.f; sn[k] = 0.f; }

    const int nv = (c == DNC - 1) ? 1 : DCH;
    const int v0 = c * DCH;
    const float* xb = x + (size_t)b * SS * HH + h;

#pragma unroll 2
    for (int i = 0; i < nv; i++) {
        int v = v0 + i;
        float hf = (v == 0 || v == SS / 4) ? 0.5f : 1.0f;  // SS/4 = 2048
        float x0 = xb[(size_t)v * HH];
        float x1 = xb[(size_t)((SS - v) & (SS - 1)) * HH];
        float x2 = xb[(size_t)(SS / 2 - v) * HH];
        float x3 = xb[(size_t)(SS / 2 + v) * HH];
        float u = (x0 + x1) * hf, d = (x0 - x1) * hf;
        float w = (x2 + x3) * hf, e = (x3 - x2) * hf;
        float upw = u + w, umw = u - w, dpe = d + e, dme = d - e;
        const float4* tw4 = (const float4*)(T + (size_t)v * 32);
#pragma unroll
        for (int j = 0; j < 8; j++) {
            float4 t = tw4[j];                 // uniform -> scalar loads
            cs[2 * j]     = fmaf(t.x, upw, cs[2 * j]);
            sn[2 * j]     = fmaf(t.y, dpe, sn[2 * j]);
            cs[2 * j + 1] = fmaf(t.z, umw, cs[2 * j + 1]);
            sn[2 * j + 1] = fmaf(t.w, dme, sn[2 * j + 1]);
        }
    }

    size_t base = ((size_t)(b * DNC + c) * MM) * (2 * HH) + h;
#pragma unroll
    for (int k = 0; k < MM; k++) {
        Xp[base + (size_t)k * (2 * HH)]      = cs[k];
        Xp[base + (size_t)k * (2 * HH) + HH] = sn[k];
    }
}

// Stage 2a: reduce partials over p.
__global__ __launch_bounds__(256) void k_reduce(const float* __restrict__ Xp,
                                                float* __restrict__ Xs) {
    const int t = blockIdx.x * 256 + threadIdx.x;
    const int INNER = MM * 2 * HH;                  // 8192
    int idx4 = t * 4;
    int inner = idx4 & (INNER - 1);
    int b = idx4 >> 13;
    const float* src = Xp + ((size_t)b * DNC) * INNER + inner;
    float4 s = make_float4(0.f, 0.f, 0.f, 0.f);
#pragma unroll 5
    for (int p = 0; p < DNC; p++) {
        float4 v = *(const float4*)(src + (size_t)p * INNER);
        s.x += v.x; s.y += v.y; s.z += v.z; s.w += v.w;
    }
    *(float4*)(Xs + idx4) = s;
}

// Stage 2b: complex mix (unchanged).
__global__ __launch_bounds__(256) void k_mix2(const float* __restrict__ Xs,
                                              const float* __restrict__ Wtr,
                                              const float* __restrict__ Wti,
                                              float* __restrict__ AB) {
    const int m = blockIdx.x, b = blockIdx.y, t = threadIdx.x;
    __shared__ float xr_s[HH], xs_s[HH];
    size_t xbase = (((size_t)b * MM + m) * 2) * HH;
    xr_s[t] = Xs[xbase + t];
    xs_s[t] = Xs[xbase + HH + t];
    __syncthreads();

    const float* wr_m = Wtr + (size_t)m * (HH * HH);
    const float* wi_m = Wti + (size_t)m * (HH * HH);
    float re = 0.f, im = 0.f;
#pragma unroll 8
    for (int h = 0; h < HH; h++) {
        float a  = wr_m[(size_t)h * HH + t];
        float bw = wi_m[(size_t)h * HH + t];
        float xr = xr_s[h];
        float xs = xs_s[h];
        re = fmaf(xr, a, re);  re = fmaf(xs, bw, re);
        im = fmaf(xr, bw, im); im = fmaf(-xs, a, im);
    }
    float scale = (m == 0 ? 1.f : 2.f) / (float)SS;
    size_t o = (((size_t)b * MM + m) * 2) * HH + t;
    AB[o]      = scale * re;
    AB[o + HH] = -scale * im;
}

// Stage 3: folded synthesis + GELU.  4 outputs per table row:
// y[v]=Pp+Qp, y[4096-v]=Pm-Qm, y[4096+v]=Pm+Qm, y[8192-v]=Pp-Qp
__global__ __launch_bounds__(256) void k_synth(const float* __restrict__ AB,
                                               const float* __restrict__ T,
                                               float* __restrict__ out) {
    const int c = blockIdx.x, b = blockIdx.y, h = threadIdx.x;
    float a[MM], bc[MM];
#pragma unroll
    for (int k = 0; k < MM; k++) {
        size_t o = (((size_t)b * MM + k) * 2) * HH + h;
        a[k]  = AB[o];
        bc[k] = AB[o + HH];
    }
    const int nv = (c == SNC - 1) ? 1 : SCH;
    const int v0 = c * SCH;
    float* ob = out + (size_t)b * SS * HH + h;

#pragma unroll 2
    for (int i = 0; i < nv; i++) {
        int v = v0 + i;
        const float4* tw4 = (const float4*)(T + (size_t)v * 32);
        float Pe = 0.f, Po = 0.f, Qe = 0.f, Qo = 0.f;
#pragma unroll
        for (int j = 0; j < 8; j++) {
            float4 t = tw4[j];
            Pe = fmaf(a[2 * j],      t.x, Pe);
            Qe = fmaf(bc[2 * j],     t.y, Qe);
            Po = fmaf(a[2 * j + 1],  t.z, Po);
            Qo = fmaf(bc[2 * j + 1], t.w, Qo);
        }
        float Pp = Pe + Po, Pm = Pe - Po, Qp = Qe + Qo, Qm = Qe - Qo;
        ob[(size_t)v * HH]                        = fast_gelu(Pp + Qp);
        ob[(size_t)(SS / 2 - v) * HH]             = fast_gelu(Pm - Qm);
        ob[(size_t)(SS / 2 + v) * HH]             = fast_gelu(Pm + Qm);
        ob[(size_t)((SS - v) & (SS - 1)) * HH]    = fast_gelu(Pp - Qp);
    }
}

extern "C" void kernel_launch(void* const* d_in, const int* in_sizes, int n_in,
                              void* d_out, int out_size, void* d_ws, size_t ws_size,
                              hipStream_t stream) {
    const float* x   = (const float*)d_in[0];
    const float* w_r = (const float*)d_in[1];
    const float* w_i = (const float*)d_in[2];
    float* out = (float*)d_out;
    float* ws  = (float*)d_ws;

    float* T   = ws;                              // NV*32 floats used
    float* AB  = ws + 262144;
    float* Xs  = ws + 393216;
    float* Xp  = out;                             // 8.5M floats scratch
    float* Wtr = out + (size_t)16 * 1024 * 1024;  // 1M floats scratch
    float* Wti = out + (size_t)17 * 1024 * 1024;  // 1M floats scratch

    hipLaunchKernelGGL(k_twiddle, dim3((NV * MM + 255) / 256), dim3(256), 0, stream, T);
    hipLaunchKernelGGL(k_wt,     dim3(HH, 2), dim3(256), 0, stream, w_r, w_i, Wtr, Wti);
    hipLaunchKernelGGL(k_dft,    dim3(DNC, BB), dim3(256), 0, stream, x, T, Xp);
    hipLaunchKernelGGL(k_reduce, dim3(BB * MM * 2 * HH / 1024), dim3(256), 0, stream, Xp, Xs);
    hipLaunchKernelGGL(k_mix2,   dim3(MM, BB), dim3(256), 0, stream, Xs, Wtr, Wti, AB);
    hipLaunchKernelGGL(k_synth,  dim3(SNC, BB), dim3(256), 0, stream, AB, T, out);
}